// Round 9
// baseline (199.111 us; speedup 1.0000x reference)
//
#include <hip/hip_runtime.h>
#include <hip/hip_bf16.h>
#include <math.h>

typedef __bf16 bf16;
typedef __bf16 bf16x4 __attribute__((ext_vector_type(4)));
typedef __bf16 bf16x8 __attribute__((ext_vector_type(8)));
typedef float  f32x4  __attribute__((ext_vector_type(4)));
typedef float  f32x16 __attribute__((ext_vector_type(16)));

#define S_LEN 2048
#define EMB   2048
#define NH    16
#define NKV   4
#define HD    128
#define FQKV  3072  /* NH*HD + 2*NKV*HD */

__device__ __forceinline__ f32x4 mfma16(bf16x8 a, bf16x8 b, f32x4 c) {
  return __builtin_amdgcn_mfma_f32_16x16x32_bf16(a, b, c, 0, 0, 0);
}
__device__ __forceinline__ f32x16 mfma32(bf16x8 a, bf16x8 b, f32x16 c) {
  return __builtin_amdgcn_mfma_f32_32x32x16_bf16(a, b, c, 0, 0, 0);
}
__device__ __forceinline__ f32x16 zero16() {
  f32x16 v;
#pragma unroll
  for (int i = 0; i < 16; ++i) v[i] = 0.f;
  return v;
}

// ---------------- f32 -> bf16 convert, 4-wide ----------------
__global__ void cvt_kernel(const float* __restrict__ in, bf16* __restrict__ out, int n4) {
  int i = blockIdx.x * blockDim.x + threadIdx.x;
  const int stride = gridDim.x * blockDim.x;
  for (; i < n4; i += stride) {
    float4 v = reinterpret_cast<const float4*>(in)[i];
    bf16x4 o;
    o[0] = (bf16)v.x; o[1] = (bf16)v.y; o[2] = (bf16)v.z; o[3] = (bf16)v.w;
    reinterpret_cast<bf16x4*>(out)[i] = o;
  }
}

// ---------------- GEMM: C[M][N] = A[M][K] * B[N][K]^T, tile 128 x BN ----------------
// BN=128 mode 0: fused RoPE/split epilogue, Q/K/V in fragment-ready TILED layouts
//   (per head, per 32-row tile T, elem addr = T*4096 + slot*256 + lq*8 + e):
//   Q/K: slot = kc*2 + hi;  V: slot = (dt*2+j)*2 + hi with kv-slot perm baked in.
// BN=64 mode 1: plain f32 store (512 blocks -> 2 blocks/CU for the dense GEMM).
template<int BN>
__global__ __launch_bounds__(256, 2) void gemm_bt(
    const bf16* __restrict__ A, const bf16* __restrict__ B,
    int M, int N, int K, int mode,
    bf16* __restrict__ qb, bf16* __restrict__ kb, bf16* __restrict__ vtb,
    float* __restrict__ outf)
{
  constexpr int NFR = BN / 16;
  __shared__ __align__(16) bf16 As[128 * 64];
  __shared__ __align__(16) bf16 Bs[BN * 64];
  const int tid = threadIdx.x;
  const int w  = tid >> 6;
  const int l  = tid & 63;
  const int li = l & 15, lh = l >> 4;
  const int m0 = blockIdx.y * 128, n0 = blockIdx.x * BN;

  f32x4 acc[2][NFR];
#pragma unroll
  for (int i = 0; i < 2; ++i)
#pragma unroll
    for (int j = 0; j < NFR; ++j) acc[i][j] = f32x4{0.f, 0.f, 0.f, 0.f};

  const int srow = l >> 3;   // row within an 8-row staging group
  const int schk = l & 7;    // 16B chunk within a 64-col row

  for (int k0 = 0; k0 < K; k0 += 64) {
#pragma unroll
    for (int i = 0; i < 4; ++i) {          // A: 128 rows
      const int row = i * 32 + w * 8 + srow;
      const int sch = schk ^ (row & 7);
      const bf16* ga = A + (size_t)(m0 + row) * K + (k0 + sch * 8);
      bf16* la = As + (i * 32 + w * 8) * 64;
      __builtin_amdgcn_global_load_lds((const __attribute__((address_space(1))) void*)ga,
                                       (__attribute__((address_space(3))) void*)la, 16, 0, 0);
    }
#pragma unroll
    for (int i = 0; i < BN / 32; ++i) {    // B: BN rows
      const int row = i * 32 + w * 8 + srow;
      const int sch = schk ^ (row & 7);
      const bf16* gb = B + (size_t)(n0 + row) * K + (k0 + sch * 8);
      bf16* lb = Bs + (i * 32 + w * 8) * 64;
      __builtin_amdgcn_global_load_lds((const __attribute__((address_space(1))) void*)gb,
                                       (__attribute__((address_space(3))) void*)lb, 16, 0, 0);
    }
    __syncthreads();
#pragma unroll
    for (int kc = 0; kc < 2; ++kc) {
      bf16x8 afr[2], bfr[NFR];
#pragma unroll
      for (int mt = 0; mt < 2; ++mt) {
        const int mr = w * 32 + mt * 16 + li;
        const int c  = (kc * 4 + lh) ^ (mr & 7);
        afr[mt] = *reinterpret_cast<const bf16x8*>((const char*)As + mr * 128 + c * 16);
      }
#pragma unroll
      for (int nt = 0; nt < NFR; ++nt) {
        const int nr = nt * 16 + li;
        const int c  = (kc * 4 + lh) ^ (nr & 7);
        bfr[nt] = *reinterpret_cast<const bf16x8*>((const char*)Bs + nr * 128 + c * 16);
      }
#pragma unroll
      for (int nt = 0; nt < NFR; ++nt) {
        acc[0][nt] = mfma16(afr[0], bfr[nt], acc[0][nt]);
        acc[1][nt] = mfma16(afr[1], bfr[nt], acc[1][nt]);
      }
    }
    __syncthreads();
  }

  // ---- epilogue ----
  const int row_base = m0 + w * 32;
  if (BN == 64 || mode == 1) {
#pragma unroll
    for (int mt = 0; mt < 2; ++mt)
#pragma unroll
      for (int nt = 0; nt < NFR; ++nt)
#pragma unroll
        for (int r = 0; r < 4; ++r) {
          const int sr = row_base + mt * 16 + lh * 4 + r;
          const int sc = n0 + nt * 16 + li;
          outf[(size_t)sr * N + sc] = acc[mt][nt][r];
        }
  } else {
    if constexpr (BN == 128) {
      int seg, hh;
      if (n0 < NH * HD)             { seg = 0; hh = n0 >> 7; }
      else if (n0 < (NH + NKV) * HD){ seg = 1; hh = (n0 - NH * HD) >> 7; }
      else                          { seg = 2; hh = (n0 - (NH + NKV) * HD) >> 7; }

      const int T = row_base >> 5;          // 32-row tile index (constant per wave)
      if (seg == 2) {
        // V tiled store: acc[mt][nt][r] = V[spos][d], spos = row_base + qp*4 + r,
        // qp = mt*4+lh; d = nt*16+li -> dt = nt>>1, lqv = (nt&1)*16+li.
        // j=(qp>>2)&1, hiv=qp&1, e = 4*((qp>>1)&1) + r
        bf16* vdst = vtb + (size_t)hh * S_LEN * HD + (size_t)T * 4096;
#pragma unroll
        for (int mt = 0; mt < 2; ++mt) {
          const int qp = mt * 4 + lh;
          const int jj = (qp >> 2) & 1, hiv = qp & 1, ebase = 4 * ((qp >> 1) & 1);
#pragma unroll
          for (int nt = 0; nt < 8; ++nt) {
            const int dt = nt >> 1;
            const int lqv = (nt & 1) * 16 + li;
            bf16x4 pk;
#pragma unroll
            for (int r = 0; r < 4; ++r) pk[r] = (bf16)acc[mt][nt][r];
            *reinterpret_cast<bf16x4*>(
                vdst + ((dt * 2 + jj) * 2 + hiv) * 256 + lqv * 8 + ebase) = pk;
          }
        }
      } else {  // Q or K: RoPE (+ 1/sqrt(D) folded into Q), tiled store
        float invf[4];
#pragma unroll
        for (int j = 0; j < 4; ++j)
          invf[j] = exp2f(-(float)(j * 16 + li) * (13.287712379549449f / 64.0f));
        bf16* dst = ((seg == 0) ? (qb + (size_t)hh * S_LEN * HD)
                                : (kb + (size_t)hh * S_LEN * HD)) + (size_t)T * 4096;
        const float qscale = (seg == 0) ? 0.08838834764831845f : 1.0f;
        const int hi2 = li >> 3, e2 = li & 7;
#pragma unroll
        for (int mt = 0; mt < 2; ++mt)
#pragma unroll
          for (int r = 0; r < 4; ++r) {
            const int spos = row_base + mt * 16 + lh * 4 + r;
            const int lqr  = spos & 31;
            float cs[4], sn[4];
#pragma unroll
            for (int j = 0; j < 4; ++j) sincosf((float)spos * invf[j], &sn[j], &cs[j]);
#pragma unroll
            for (int nt = 0; nt < 8; ++nt) {
              const int j = nt & 3;
              const float x = acc[mt][nt][r];
              const float prt = acc[mt][nt ^ 4][r];
              const float rot = (nt < 4) ? -prt : prt;
              const float y = (x * cs[j] + rot * sn[j]) * qscale;
              dst[(nt * 2 + hi2) * 256 + lqr * 8 + e2] = (bf16)y;
            }
          }
      }
    }
  }
}

// ---------------- flash attention: XCD-affine persistent queues ----------------
// 768 blocks; queue x = blockIdx.x & 7 (XCD round-robin heuristic). Queue x
// serves heads {2x, 2x+1} (kh = x>>1 fixed -> its 1MB K/V stays in that XCD's
// L2), qt descending. 4 waves per block on the same 32 q-rows; wave w takes
// kv-tiles kv0 = w*32 + 128t. All loads contiguous 1KB wave-loads.
__global__ __launch_bounds__(256, 3) void attn_kernel(
    const bf16* __restrict__ qb, const bf16* __restrict__ kb, const bf16* __restrict__ vtb,
    bf16* __restrict__ ctx, int* __restrict__ wcnt)
{
  __shared__ float Ml[4][32], Ll[4][32], Lgl[32];
  __shared__ float Obuf[32][129];
  __shared__ int sitem;

  const int tid = threadIdx.x;
  const int w  = tid >> 6;
  const int l  = tid & 63;
  const int lq = l & 31;
  const int hi = l >> 5;
  const int xcd = (int)blockIdx.x & 7;

  const float L2E = 1.4426950408889634f;
  const float BIG = -3.0e38f;

  for (;;) {
    if (tid == 0) sitem = atomicAdd(&wcnt[xcd * 32], 1);
    __syncthreads();
    const int il = sitem;
    if (il >= 2 * (S_LEN / 32)) break;

    const int qt = 63 - (il >> 1);     // longest first
    const int h  = (xcd << 1) | (il & 1);
    const int q0 = qt * 32;
    const int kh = h >> 2;

    const bf16* Qh = qb + (size_t)h * S_LEN * HD;
    const bf16* Kh = kb + (size_t)kh * S_LEN * HD;
    const bf16* Vh = vtb + (size_t)kh * S_LEN * HD;

    // hoist Q fragments (coalesced 1KB per load)
    const bf16* qtile = Qh + (size_t)qt * 4096;
    bf16x8 qfr[8];
#pragma unroll
    for (int kc = 0; kc < 8; ++kc)
      qfr[kc] = *reinterpret_cast<const bf16x8*>(qtile + (kc * 2 + hi) * 256 + lq * 8);

    f32x16 o[4];
#pragma unroll
    for (int dt = 0; dt < 4; ++dt) o[dt] = zero16();
    float mrow = BIG, lrow = 0.f;

    for (int kv0 = w * 32; kv0 < q0 + 32; kv0 += 128) {
      const bf16* ktile = Kh + (size_t)(kv0 >> 5) * 4096;
      const bf16* vtile = Vh + (size_t)(kv0 >> 5) * 4096;
      // ---- issue V first (needed only after softmax), then K ----
      bf16x8 va[8];
#pragma unroll
      for (int sv = 0; sv < 8; ++sv)
        va[sv] = *reinterpret_cast<const bf16x8*>(vtile + (sv * 2 + hi) * 256 + lq * 8);
      bf16x8 kf[8];
#pragma unroll
      for (int kc = 0; kc < 8; ++kc)
        kf[kc] = *reinterpret_cast<const bf16x8*>(ktile + (kc * 2 + hi) * 256 + lq * 8);
      // ---- QK^T: S^T[kv][q], two chains of 4 ----
      f32x16 sa = zero16(), sb = zero16();
      __builtin_amdgcn_s_setprio(1);
#pragma unroll
      for (int kc = 0; kc < 4; ++kc) {
        sa = mfma32(kf[kc], qfr[kc], sa);
        sb = mfma32(kf[kc + 4], qfr[kc + 4], sb);
      }
      __builtin_amdgcn_s_setprio(0);
      f32x16 s = sa + sb;
      // ---- causal mask (diagonal tiles only) ----
      const int q = q0 + lq;
      if (kv0 + 31 > q0) {
#pragma unroll
        for (int r = 0; r < 16; ++r) {
          const int kvv = (r & 3) + 8 * (r >> 2) + 4 * hi;
          if (kv0 + kvv > q) s[r] = BIG;
        }
      }
      // ---- in-register online softmax with defer-max (THR=8) ----
      float pm = s[0];
#pragma unroll
      for (int r = 1; r < 16; ++r) pm = fmaxf(pm, s[r]);
      pm = fmaxf(pm, __shfl_xor(pm, 32));
      if (__any(pm > mrow + 8.f)) {
        const float mnew = fmaxf(mrow, pm);
        const float sc = (mrow < -1.0e37f) ? 0.f : exp2f((mrow - mnew) * L2E);
        mrow = mnew;
        lrow *= sc;
#pragma unroll
        for (int dt = 0; dt < 4; ++dt) o[dt] = o[dt] * sc;
      }
      bf16x8 pb0, pb1;
      float tsum = 0.f;
#pragma unroll
      for (int r = 0; r < 8; ++r) {
        const float pv = exp2f((s[r] - mrow) * L2E);
        tsum += pv; pb0[r] = (bf16)pv;
      }
#pragma unroll
      for (int r = 0; r < 8; ++r) {
        const float pv = exp2f((s[8 + r] - mrow) * L2E);
        tsum += pv; pb1[r] = (bf16)pv;
      }
      tsum += __shfl_xor(tsum, 32);
      lrow += tsum;
      // ---- PV ----
      __builtin_amdgcn_s_setprio(1);
#pragma unroll
      for (int dt = 0; dt < 4; ++dt) {
        o[dt] = mfma32(va[2 * dt], pb0, o[dt]);
        o[dt] = mfma32(va[2 * dt + 1], pb1, o[dt]);
      }
      __builtin_amdgcn_s_setprio(0);
    }

    // ---- merge the 4 KV-split partials ----
    if (hi == 0) { Ml[w][lq] = mrow; Ll[w][lq] = lrow; }
    __syncthreads();
    const float m0v = Ml[0][lq], m1v = Ml[1][lq], m2v = Ml[2][lq], m3v = Ml[3][lq];
    const float mg = fmaxf(fmaxf(m0v, m1v), fmaxf(m2v, m3v));
    const float lg = Ll[0][lq] * exp2f((m0v - mg) * L2E)
                   + Ll[1][lq] * exp2f((m1v - mg) * L2E)
                   + Ll[2][lq] * exp2f((m2v - mg) * L2E)
                   + Ll[3][lq] * exp2f((m3v - mg) * L2E);
    const float sc2 = (mrow < -1.0e37f) ? 0.f : exp2f((mrow - mg) * L2E);
    if (w == 0 && hi == 0) Lgl[lq] = lg;
#pragma unroll
    for (int pass = 0; pass < 4; ++pass) {
      if (w == pass) {
#pragma unroll
        for (int dt = 0; dt < 4; ++dt)
#pragma unroll
          for (int r = 0; r < 16; ++r) {
            const int d = dt * 32 + (r & 3) + 8 * (r >> 2) + 4 * hi;
            const float v = o[dt][r] * sc2;
            if (pass == 0) Obuf[lq][d] = v; else Obuf[lq][d] += v;
          }
      }
      __syncthreads();
    }
    // ---- epilogue ----
    {
      const int row = tid >> 3;
      const int d0 = (tid & 7) * 16;
      const float linv = 1.0f / Lgl[row];
      bf16x8 pk0, pk1;
#pragma unroll
      for (int j = 0; j < 8; ++j) {
        pk0[j] = (bf16)(Obuf[row][d0 + j] * linv);
        pk1[j] = (bf16)(Obuf[row][d0 + 8 + j] * linv);
      }
      bf16* dst = ctx + (size_t)(q0 + row) * (NH * HD) + h * HD + d0;
      *reinterpret_cast<bf16x8*>(dst) = pk0;
      *reinterpret_cast<bf16x8*>(dst + 8) = pk1;
    }
  }
}

extern "C" void kernel_launch(void* const* d_in, const int* in_sizes, int n_in,
                              void* d_out, int out_size, void* d_ws, size_t ws_size,
                              hipStream_t stream)
{
  const float* x       = (const float*)d_in[0];
  const float* w_qkv   = (const float*)d_in[1];
  const float* w_dense = (const float*)d_in[2];
  float* out = (float*)d_out;

  char* ws = (char*)d_ws;
  size_t off = 0;
  bf16* xb    = (bf16*)(ws + off); off += (size_t)S_LEN * EMB * 2;
  bf16* wqkvb = (bf16*)(ws + off); off += (size_t)FQKV * EMB * 2;
  bf16* wdb   = (bf16*)(ws + off); off += (size_t)EMB * EMB * 2;
  bf16* qbuf  = (bf16*)(ws + off); off += (size_t)NH  * S_LEN * HD * 2;
  bf16* kbuf  = (bf16*)(ws + off); off += (size_t)NKV * S_LEN * HD * 2;
  bf16* vfbuf = (bf16*)(ws + off); off += (size_t)NKV * HD * S_LEN * 2;
  bf16* ctxb  = (bf16*)(ws + off); off += (size_t)S_LEN * NH * HD * 2;
  int*  wcnt  = (int*)(ws + off);  off += 8 * 32 * sizeof(int);
  (void)ws_size; (void)in_sizes; (void)n_in; (void)out_size;

  cvt_kernel<<<2048, 256, 0, stream>>>(x,       xb,    S_LEN * EMB / 4);
  cvt_kernel<<<2048, 256, 0, stream>>>(w_qkv,   wqkvb, FQKV * EMB / 4);
  cvt_kernel<<<2048, 256, 0, stream>>>(w_dense, wdb,   EMB * EMB / 4);

  gemm_bt<128><<<dim3(FQKV / 128, S_LEN / 128), 256, 0, stream>>>(
      xb, wqkvb, S_LEN, FQKV, EMB, 0, qbuf, kbuf, vfbuf, nullptr);

  hipMemsetAsync(wcnt, 0, 8 * 32 * sizeof(int), stream);

  attn_kernel<<<768, 256, 0, stream>>>(qbuf, kbuf, vfbuf, ctxb, wcnt);

  gemm_bt<64><<<dim3(EMB / 64, S_LEN / 128), 256, 0, stream>>>(
      ctxb, wdb, S_LEN, EMB, NH * HD, 1, nullptr, nullptr, nullptr, out);
}

// Round 10
// 174.392 us; speedup vs baseline: 1.1417x; 1.1417x over previous
//
#include <hip/hip_runtime.h>
#include <hip/hip_bf16.h>
#include <math.h>

typedef __bf16 bf16;
typedef __bf16 bf16x4 __attribute__((ext_vector_type(4)));
typedef __bf16 bf16x8 __attribute__((ext_vector_type(8)));
typedef float  f32x4  __attribute__((ext_vector_type(4)));
typedef float  f32x16 __attribute__((ext_vector_type(16)));

#define S_LEN 2048
#define EMB   2048
#define NH    16
#define NKV   4
#define HD    128
#define FQKV  3072  /* NH*HD + 2*NKV*HD */

__device__ __forceinline__ f32x4 mfma16(bf16x8 a, bf16x8 b, f32x4 c) {
  return __builtin_amdgcn_mfma_f32_16x16x32_bf16(a, b, c, 0, 0, 0);
}
__device__ __forceinline__ f32x16 mfma32(bf16x8 a, bf16x8 b, f32x16 c) {
  return __builtin_amdgcn_mfma_f32_32x32x16_bf16(a, b, c, 0, 0, 0);
}
__device__ __forceinline__ f32x16 zero16() {
  f32x16 v;
#pragma unroll
  for (int i = 0; i < 16; ++i) v[i] = 0.f;
  return v;
}

// ---------------- f32 -> bf16 convert, 4-wide ----------------
__global__ void cvt_kernel(const float* __restrict__ in, bf16* __restrict__ out, int n4) {
  int i = blockIdx.x * blockDim.x + threadIdx.x;
  const int stride = gridDim.x * blockDim.x;
  for (; i < n4; i += stride) {
    float4 v = reinterpret_cast<const float4*>(in)[i];
    bf16x4 o;
    o[0] = (bf16)v.x; o[1] = (bf16)v.y; o[2] = (bf16)v.z; o[3] = (bf16)v.w;
    reinterpret_cast<bf16x4*>(out)[i] = o;
  }
}

// ---------------- GEMM: C[M][N] = A[M][K] * B[N][K]^T, tile 128 x BN ----------------
// BN=128 mode 0: fused RoPE/split epilogue, Q/K/V in fragment-ready TILED layouts
//   (per head, per 32-row tile T, elem addr = T*4096 + slot*256 + lq*8 + e):
//   Q/K: slot = kc*2 + hi;  V: slot = (dt*2+j)*2 + hi with kv-slot perm baked in.
// BN=64 mode 1: plain f32 store (512 blocks -> 2 blocks/CU for the dense GEMM).
template<int BN>
__global__ __launch_bounds__(256, 2) void gemm_bt(
    const bf16* __restrict__ A, const bf16* __restrict__ B,
    int M, int N, int K, int mode,
    bf16* __restrict__ qb, bf16* __restrict__ kb, bf16* __restrict__ vtb,
    float* __restrict__ outf)
{
  constexpr int NFR = BN / 16;
  __shared__ __align__(16) bf16 As[128 * 64];
  __shared__ __align__(16) bf16 Bs[BN * 64];
  const int tid = threadIdx.x;
  const int w  = tid >> 6;
  const int l  = tid & 63;
  const int li = l & 15, lh = l >> 4;
  const int m0 = blockIdx.y * 128, n0 = blockIdx.x * BN;

  f32x4 acc[2][NFR];
#pragma unroll
  for (int i = 0; i < 2; ++i)
#pragma unroll
    for (int j = 0; j < NFR; ++j) acc[i][j] = f32x4{0.f, 0.f, 0.f, 0.f};

  const int srow = l >> 3;   // row within an 8-row staging group
  const int schk = l & 7;    // 16B chunk within a 64-col row

  for (int k0 = 0; k0 < K; k0 += 64) {
#pragma unroll
    for (int i = 0; i < 4; ++i) {          // A: 128 rows
      const int row = i * 32 + w * 8 + srow;
      const int sch = schk ^ (row & 7);
      const bf16* ga = A + (size_t)(m0 + row) * K + (k0 + sch * 8);
      bf16* la = As + (i * 32 + w * 8) * 64;
      __builtin_amdgcn_global_load_lds((const __attribute__((address_space(1))) void*)ga,
                                       (__attribute__((address_space(3))) void*)la, 16, 0, 0);
    }
#pragma unroll
    for (int i = 0; i < BN / 32; ++i) {    // B: BN rows
      const int row = i * 32 + w * 8 + srow;
      const int sch = schk ^ (row & 7);
      const bf16* gb = B + (size_t)(n0 + row) * K + (k0 + sch * 8);
      bf16* lb = Bs + (i * 32 + w * 8) * 64;
      __builtin_amdgcn_global_load_lds((const __attribute__((address_space(1))) void*)gb,
                                       (__attribute__((address_space(3))) void*)lb, 16, 0, 0);
    }
    __syncthreads();
#pragma unroll
    for (int kc = 0; kc < 2; ++kc) {
      bf16x8 afr[2], bfr[NFR];
#pragma unroll
      for (int mt = 0; mt < 2; ++mt) {
        const int mr = w * 32 + mt * 16 + li;
        const int c  = (kc * 4 + lh) ^ (mr & 7);
        afr[mt] = *reinterpret_cast<const bf16x8*>((const char*)As + mr * 128 + c * 16);
      }
#pragma unroll
      for (int nt = 0; nt < NFR; ++nt) {
        const int nr = nt * 16 + li;
        const int c  = (kc * 4 + lh) ^ (nr & 7);
        bfr[nt] = *reinterpret_cast<const bf16x8*>((const char*)Bs + nr * 128 + c * 16);
      }
#pragma unroll
      for (int nt = 0; nt < NFR; ++nt) {
        acc[0][nt] = mfma16(afr[0], bfr[nt], acc[0][nt]);
        acc[1][nt] = mfma16(afr[1], bfr[nt], acc[1][nt]);
      }
    }
    __syncthreads();
  }

  // ---- epilogue ----
  const int row_base = m0 + w * 32;
  if (BN == 64 || mode == 1) {
#pragma unroll
    for (int mt = 0; mt < 2; ++mt)
#pragma unroll
      for (int nt = 0; nt < NFR; ++nt)
#pragma unroll
        for (int r = 0; r < 4; ++r) {
          const int sr = row_base + mt * 16 + lh * 4 + r;
          const int sc = n0 + nt * 16 + li;
          outf[(size_t)sr * N + sc] = acc[mt][nt][r];
        }
  } else {
    if constexpr (BN == 128) {
      int seg, hh;
      if (n0 < NH * HD)             { seg = 0; hh = n0 >> 7; }
      else if (n0 < (NH + NKV) * HD){ seg = 1; hh = (n0 - NH * HD) >> 7; }
      else                          { seg = 2; hh = (n0 - (NH + NKV) * HD) >> 7; }

      const int T = row_base >> 5;          // 32-row tile index (constant per wave)
      if (seg == 2) {
        // V tiled store: acc[mt][nt][r] = V[spos][d], spos = row_base + qp*4 + r,
        // qp = mt*4+lh; d = nt*16+li -> dt = nt>>1, lqv = (nt&1)*16+li.
        // j=(qp>>2)&1, hiv=qp&1, e = 4*((qp>>1)&1) + r
        bf16* vdst = vtb + (size_t)hh * S_LEN * HD + (size_t)T * 4096;
#pragma unroll
        for (int mt = 0; mt < 2; ++mt) {
          const int qp = mt * 4 + lh;
          const int jj = (qp >> 2) & 1, hiv = qp & 1, ebase = 4 * ((qp >> 1) & 1);
#pragma unroll
          for (int nt = 0; nt < 8; ++nt) {
            const int dt = nt >> 1;
            const int lqv = (nt & 1) * 16 + li;
            bf16x4 pk;
#pragma unroll
            for (int r = 0; r < 4; ++r) pk[r] = (bf16)acc[mt][nt][r];
            *reinterpret_cast<bf16x4*>(
                vdst + ((dt * 2 + jj) * 2 + hiv) * 256 + lqv * 8 + ebase) = pk;
          }
        }
      } else {  // Q or K: RoPE (+ 1/sqrt(D) folded into Q), tiled store
        float invf[4];
#pragma unroll
        for (int j = 0; j < 4; ++j)
          invf[j] = exp2f(-(float)(j * 16 + li) * (13.287712379549449f / 64.0f));
        bf16* dst = ((seg == 0) ? (qb + (size_t)hh * S_LEN * HD)
                                : (kb + (size_t)hh * S_LEN * HD)) + (size_t)T * 4096;
        const float qscale = (seg == 0) ? 0.08838834764831845f : 1.0f;
        const int hi2 = li >> 3, e2 = li & 7;
#pragma unroll
        for (int mt = 0; mt < 2; ++mt)
#pragma unroll
          for (int r = 0; r < 4; ++r) {
            const int spos = row_base + mt * 16 + lh * 4 + r;
            const int lqr  = spos & 31;
            float cs[4], sn[4];
#pragma unroll
            for (int j = 0; j < 4; ++j) sincosf((float)spos * invf[j], &sn[j], &cs[j]);
#pragma unroll
            for (int nt = 0; nt < 8; ++nt) {
              const int j = nt & 3;
              const float x = acc[mt][nt][r];
              const float prt = acc[mt][nt ^ 4][r];
              const float rot = (nt < 4) ? -prt : prt;
              const float y = (x * cs[j] + rot * sn[j]) * qscale;
              dst[(nt * 2 + hi2) * 256 + lqr * 8 + e2] = (bf16)y;
            }
          }
      }
    }
  }
}

// ---------------- flash attention: LDS-shared K/V, 2 waves / 64 q-rows ----------------
// Block = 128 threads (2 waves). Wave ws owns q-rows [q0+32ws, q0+32ws+32).
// Both waves share every KV tile staged in LDS (wave0 stages K, wave1 stages V
// via global_load_lds, double-buffered; one vmcnt+barrier per tile). This halves
// per-wave L2 traffic (r8 was at ~87% of the per-CU L2 port). No kv-split ->
// no merge phase. Static grid pairing: blocks b and b+256 (same CU under the
// round-robin heuristic) get qp and 31-qp -> per-CU work constant (66 iters).
__global__ __launch_bounds__(128, 1) void attn_kernel(
    const bf16* __restrict__ qb, const bf16* __restrict__ kb, const bf16* __restrict__ vtb,
    bf16* __restrict__ ctx)
{
  __shared__ __align__(16) bf16 Kst[2][4096];
  __shared__ __align__(16) bf16 Vst[2][4096];
  __shared__ float Ob[2][32][129];

  const int tid = threadIdx.x;
  const int ws = tid >> 6;      // wave id (0: stages K, 1: stages V)
  const int l  = tid & 63;
  const int lq = l & 31;
  const int hi = l >> 5;
  const int b  = (int)blockIdx.x;
  const int qp = (b < 256) ? (31 - (b >> 4)) : ((b - 256) >> 4);
  const int h  = b & 15;
  const int q0w = qp * 64 + ws * 32;   // this wave's q-subtile base
  const int kh  = h >> 2;
  const int nt  = 2 * qp + 2;          // staged tiles (wave1's range)
  const int ntw = 2 * qp + 1 + ws;     // tiles this wave computes

  const bf16* Qh = qb + (size_t)h * S_LEN * HD;
  const bf16* Kh = kb + (size_t)kh * S_LEN * HD;
  const bf16* Vh = vtb + (size_t)kh * S_LEN * HD;
  const bf16* stsrc = ws ? Vh : Kh;    // this wave's staging source

  const float L2E = 1.4426950408889634f;
  const float BIG = -3.0e38f;

  // hoist Q fragments (coalesced 1KB loads from tiled layout)
  const bf16* qtile = Qh + (size_t)(q0w >> 5) * 4096;
  bf16x8 qfr[8];
#pragma unroll
  for (int kc = 0; kc < 8; ++kc)
    qfr[kc] = *reinterpret_cast<const bf16x8*>(qtile + (kc * 2 + hi) * 256 + lq * 8);

  f32x16 o[4];
#pragma unroll
  for (int dt = 0; dt < 4; ++dt) o[dt] = zero16();
  float mrow = BIG, lrow = 0.f;

  // ---- stage tile 0 ----
  {
    const bf16* src = stsrc + l * 8;
    bf16* dst = ws ? Vst[0] : Kst[0];
#pragma unroll
    for (int c = 0; c < 8; ++c)
      __builtin_amdgcn_global_load_lds(
          (const __attribute__((address_space(1))) void*)(src + c * 512),
          (__attribute__((address_space(3))) void*)(dst + c * 512), 16, 0, 0);
  }
  __syncthreads();   // drains vmcnt before barrier (compiler semantics)

  for (int t = 0; t < nt; ++t) {
    const int cur = t & 1;
    // ---- issue next tile's staging early (hides under compute) ----
    if (t + 1 < nt) {
      const bf16* src = stsrc + (size_t)(t + 1) * 4096 + l * 8;
      bf16* dst = ws ? Vst[cur ^ 1] : Kst[cur ^ 1];
#pragma unroll
      for (int c = 0; c < 8; ++c)
        __builtin_amdgcn_global_load_lds(
            (const __attribute__((address_space(1))) void*)(src + c * 512),
            (__attribute__((address_space(3))) void*)(dst + c * 512), 16, 0, 0);
    }
    if (t < ntw) {
      const bf16* kcur = Kst[cur];
      const bf16* vcur = Vst[cur];
      const int kv0 = t * 32;
      // ---- QK^T from LDS: S^T[kv][q], two chains of 4 ----
      bf16x8 kf[8];
#pragma unroll
      for (int kc = 0; kc < 8; ++kc)
        kf[kc] = *reinterpret_cast<const bf16x8*>(kcur + (kc * 2 + hi) * 256 + lq * 8);
      f32x16 sa = zero16(), sb = zero16();
      __builtin_amdgcn_s_setprio(1);
#pragma unroll
      for (int kc = 0; kc < 4; ++kc) {
        sa = mfma32(kf[kc], qfr[kc], sa);
        sb = mfma32(kf[kc + 4], qfr[kc + 4], sb);
      }
      __builtin_amdgcn_s_setprio(0);
      f32x16 s = sa + sb;
      // ---- causal mask (diagonal tiles only) ----
      const int q = q0w + lq;
      if (kv0 + 31 > q0w) {
#pragma unroll
        for (int r = 0; r < 16; ++r) {
          const int kvv = (r & 3) + 8 * (r >> 2) + 4 * hi;
          if (kv0 + kvv > q) s[r] = BIG;
        }
      }
      // ---- in-register online softmax with defer-max (THR=8) ----
      float pm = s[0];
#pragma unroll
      for (int r = 1; r < 16; ++r) pm = fmaxf(pm, s[r]);
      pm = fmaxf(pm, __shfl_xor(pm, 32));
      if (__any(pm > mrow + 8.f)) {
        const float mnew = fmaxf(mrow, pm);
        const float sc = (mrow < -1.0e37f) ? 0.f : exp2f((mrow - mnew) * L2E);
        mrow = mnew;
        lrow *= sc;
#pragma unroll
        for (int dt = 0; dt < 4; ++dt) o[dt] = o[dt] * sc;
      }
      bf16x8 pb0, pb1;
      float tsum = 0.f;
#pragma unroll
      for (int r = 0; r < 8; ++r) {
        const float pv = exp2f((s[r] - mrow) * L2E);
        tsum += pv; pb0[r] = (bf16)pv;
      }
#pragma unroll
      for (int r = 0; r < 8; ++r) {
        const float pv = exp2f((s[8 + r] - mrow) * L2E);
        tsum += pv; pb1[r] = (bf16)pv;
      }
      tsum += __shfl_xor(tsum, 32);
      lrow += tsum;
      // ---- PV from LDS ----
      bf16x8 va[8];
#pragma unroll
      for (int sv = 0; sv < 8; ++sv)
        va[sv] = *reinterpret_cast<const bf16x8*>(vcur + (sv * 2 + hi) * 256 + lq * 8);
      __builtin_amdgcn_s_setprio(1);
#pragma unroll
      for (int dt = 0; dt < 4; ++dt) {
        o[dt] = mfma32(va[2 * dt], pb0, o[dt]);
        o[dt] = mfma32(va[2 * dt + 1], pb1, o[dt]);
      }
      __builtin_amdgcn_s_setprio(0);
    }
    __syncthreads();   // staged tile complete + all reads of cur done
  }

  // ---- epilogue: per-wave LDS transpose, coalesced bf16 write ----
  {
    const float linv = 1.0f / lrow;
#pragma unroll
    for (int dt = 0; dt < 4; ++dt)
#pragma unroll
      for (int r = 0; r < 16; ++r) {
        const int d = dt * 32 + (r & 3) + 8 * (r >> 2) + 4 * hi;
        Ob[ws][lq][d] = o[dt][r] * linv;
      }
    __syncthreads();
    const int row = l >> 1;
    const int dh  = (l & 1) * 64;
#pragma unroll
    for (int j = 0; j < 8; ++j) {
      bf16x8 pk;
#pragma unroll
      for (int e = 0; e < 8; ++e) pk[e] = (bf16)Ob[ws][row][dh + j * 8 + e];
      *reinterpret_cast<bf16x8*>(
          ctx + (size_t)(q0w + row) * (NH * HD) + h * HD + dh + j * 8) = pk;
    }
  }
}

extern "C" void kernel_launch(void* const* d_in, const int* in_sizes, int n_in,
                              void* d_out, int out_size, void* d_ws, size_t ws_size,
                              hipStream_t stream)
{
  const float* x       = (const float*)d_in[0];
  const float* w_qkv   = (const float*)d_in[1];
  const float* w_dense = (const float*)d_in[2];
  float* out = (float*)d_out;

  char* ws = (char*)d_ws;
  size_t off = 0;
  bf16* xb    = (bf16*)(ws + off); off += (size_t)S_LEN * EMB * 2;
  bf16* wqkvb = (bf16*)(ws + off); off += (size_t)FQKV * EMB * 2;
  bf16* wdb   = (bf16*)(ws + off); off += (size_t)EMB * EMB * 2;
  bf16* qbuf  = (bf16*)(ws + off); off += (size_t)NH  * S_LEN * HD * 2;
  bf16* kbuf  = (bf16*)(ws + off); off += (size_t)NKV * S_LEN * HD * 2;
  bf16* vfbuf = (bf16*)(ws + off); off += (size_t)NKV * HD * S_LEN * 2;
  bf16* ctxb  = (bf16*)(ws + off); off += (size_t)S_LEN * NH * HD * 2;
  (void)ws_size; (void)in_sizes; (void)n_in; (void)out_size;

  cvt_kernel<<<2048, 256, 0, stream>>>(x,       xb,    S_LEN * EMB / 4);
  cvt_kernel<<<2048, 256, 0, stream>>>(w_qkv,   wqkvb, FQKV * EMB / 4);
  cvt_kernel<<<2048, 256, 0, stream>>>(w_dense, wdb,   EMB * EMB / 4);

  gemm_bt<128><<<dim3(FQKV / 128, S_LEN / 128), 256, 0, stream>>>(
      xb, wqkvb, S_LEN, FQKV, EMB, 0, qbuf, kbuf, vfbuf, nullptr);

  attn_kernel<<<512, 128, 0, stream>>>(qbuf, kbuf, vfbuf, ctxb);

  gemm_bt<64><<<dim3(EMB / 64, S_LEN / 128), 256, 0, stream>>>(
      ctxb, wdb, S_LEN, EMB, NH * HD, 1, nullptr, nullptr, nullptr, out);
}

// Round 11
// 162.356 us; speedup vs baseline: 1.2264x; 1.0741x over previous
//
#include <hip/hip_runtime.h>
#include <hip/hip_bf16.h>
#include <math.h>

typedef __bf16 bf16;
typedef __bf16 bf16x4 __attribute__((ext_vector_type(4)));
typedef __bf16 bf16x8 __attribute__((ext_vector_type(8)));
typedef float  f32x4  __attribute__((ext_vector_type(4)));
typedef float  f32x16 __attribute__((ext_vector_type(16)));

#define S_LEN 2048
#define EMB   2048
#define NH    16
#define NKV   4
#define HD    128
#define FQKV  3072  /* NH*HD + 2*NKV*HD */

__device__ __forceinline__ f32x4 mfma16(bf16x8 a, bf16x8 b, f32x4 c) {
  return __builtin_amdgcn_mfma_f32_16x16x32_bf16(a, b, c, 0, 0, 0);
}
__device__ __forceinline__ f32x16 mfma32(bf16x8 a, bf16x8 b, f32x16 c) {
  return __builtin_amdgcn_mfma_f32_32x32x16_bf16(a, b, c, 0, 0, 0);
}
__device__ __forceinline__ f32x16 zero16() {
  f32x16 v;
#pragma unroll
  for (int i = 0; i < 16; ++i) v[i] = 0.f;
  return v;
}

// ---------------- f32 -> bf16 convert, 4-wide ----------------
__global__ void cvt_kernel(const float* __restrict__ in, bf16* __restrict__ out, int n4) {
  int i = blockIdx.x * blockDim.x + threadIdx.x;
  const int stride = gridDim.x * blockDim.x;
  for (; i < n4; i += stride) {
    float4 v = reinterpret_cast<const float4*>(in)[i];
    bf16x4 o;
    o[0] = (bf16)v.x; o[1] = (bf16)v.y; o[2] = (bf16)v.z; o[3] = (bf16)v.w;
    reinterpret_cast<bf16x4*>(out)[i] = o;
  }
}

// ---------------- GEMM: C[M][N] = A[M][K] * B[N][K]^T, tile 128 x BN ----------------
// BN=128 mode 0: fused RoPE/split epilogue, Q/K/V in fragment-ready TILED layouts
//   (per head, per 32-row tile T, elem addr = T*4096 + slot*256 + lq*8 + e):
//   Q/K: slot = kc*2 + hi;  V: slot = (dt*2+j)*2 + hi with kv-slot perm baked in.
// BN=64 mode 1: plain f32 store (512 blocks -> 2 blocks/CU for the dense GEMM).
template<int BN>
__global__ __launch_bounds__(256, 2) void gemm_bt(
    const bf16* __restrict__ A, const bf16* __restrict__ B,
    int M, int N, int K, int mode,
    bf16* __restrict__ qb, bf16* __restrict__ kb, bf16* __restrict__ vtb,
    float* __restrict__ outf)
{
  constexpr int NFR = BN / 16;
  __shared__ __align__(16) bf16 As[128 * 64];
  __shared__ __align__(16) bf16 Bs[BN * 64];
  const int tid = threadIdx.x;
  const int w  = tid >> 6;
  const int l  = tid & 63;
  const int li = l & 15, lh = l >> 4;
  const int m0 = blockIdx.y * 128, n0 = blockIdx.x * BN;

  f32x4 acc[2][NFR];
#pragma unroll
  for (int i = 0; i < 2; ++i)
#pragma unroll
    for (int j = 0; j < NFR; ++j) acc[i][j] = f32x4{0.f, 0.f, 0.f, 0.f};

  const int srow = l >> 3;   // row within an 8-row staging group
  const int schk = l & 7;    // 16B chunk within a 64-col row

  for (int k0 = 0; k0 < K; k0 += 64) {
#pragma unroll
    for (int i = 0; i < 4; ++i) {          // A: 128 rows
      const int row = i * 32 + w * 8 + srow;
      const int sch = schk ^ (row & 7);
      const bf16* ga = A + (size_t)(m0 + row) * K + (k0 + sch * 8);
      bf16* la = As + (i * 32 + w * 8) * 64;
      __builtin_amdgcn_global_load_lds((const __attribute__((address_space(1))) void*)ga,
                                       (__attribute__((address_space(3))) void*)la, 16, 0, 0);
    }
#pragma unroll
    for (int i = 0; i < BN / 32; ++i) {    // B: BN rows
      const int row = i * 32 + w * 8 + srow;
      const int sch = schk ^ (row & 7);
      const bf16* gb = B + (size_t)(n0 + row) * K + (k0 + sch * 8);
      bf16* lb = Bs + (i * 32 + w * 8) * 64;
      __builtin_amdgcn_global_load_lds((const __attribute__((address_space(1))) void*)gb,
                                       (__attribute__((address_space(3))) void*)lb, 16, 0, 0);
    }
    __syncthreads();
#pragma unroll
    for (int kc = 0; kc < 2; ++kc) {
      bf16x8 afr[2], bfr[NFR];
#pragma unroll
      for (int mt = 0; mt < 2; ++mt) {
        const int mr = w * 32 + mt * 16 + li;
        const int c  = (kc * 4 + lh) ^ (mr & 7);
        afr[mt] = *reinterpret_cast<const bf16x8*>((const char*)As + mr * 128 + c * 16);
      }
#pragma unroll
      for (int nt = 0; nt < NFR; ++nt) {
        const int nr = nt * 16 + li;
        const int c  = (kc * 4 + lh) ^ (nr & 7);
        bfr[nt] = *reinterpret_cast<const bf16x8*>((const char*)Bs + nr * 128 + c * 16);
      }
#pragma unroll
      for (int nt = 0; nt < NFR; ++nt) {
        acc[0][nt] = mfma16(afr[0], bfr[nt], acc[0][nt]);
        acc[1][nt] = mfma16(afr[1], bfr[nt], acc[1][nt]);
      }
    }
    __syncthreads();
  }

  // ---- epilogue ----
  const int row_base = m0 + w * 32;
  if (BN == 64 || mode == 1) {
#pragma unroll
    for (int mt = 0; mt < 2; ++mt)
#pragma unroll
      for (int nt = 0; nt < NFR; ++nt)
#pragma unroll
        for (int r = 0; r < 4; ++r) {
          const int sr = row_base + mt * 16 + lh * 4 + r;
          const int sc = n0 + nt * 16 + li;
          outf[(size_t)sr * N + sc] = acc[mt][nt][r];
        }
  } else {
    if constexpr (BN == 128) {
      int seg, hh;
      if (n0 < NH * HD)             { seg = 0; hh = n0 >> 7; }
      else if (n0 < (NH + NKV) * HD){ seg = 1; hh = (n0 - NH * HD) >> 7; }
      else                          { seg = 2; hh = (n0 - (NH + NKV) * HD) >> 7; }

      const int T = row_base >> 5;          // 32-row tile index (constant per wave)
      if (seg == 2) {
        // V tiled store: acc[mt][nt][r] = V[spos][d], spos = row_base + qp*4 + r,
        // qp = mt*4+lh; d = nt*16+li -> dt = nt>>1, lqv = (nt&1)*16+li.
        // j=(qp>>2)&1, hiv=qp&1, e = 4*((qp>>1)&1) + r
        bf16* vdst = vtb + (size_t)hh * S_LEN * HD + (size_t)T * 4096;
#pragma unroll
        for (int mt = 0; mt < 2; ++mt) {
          const int qp = mt * 4 + lh;
          const int jj = (qp >> 2) & 1, hiv = qp & 1, ebase = 4 * ((qp >> 1) & 1);
#pragma unroll
          for (int nt = 0; nt < 8; ++nt) {
            const int dt = nt >> 1;
            const int lqv = (nt & 1) * 16 + li;
            bf16x4 pk;
#pragma unroll
            for (int r = 0; r < 4; ++r) pk[r] = (bf16)acc[mt][nt][r];
            *reinterpret_cast<bf16x4*>(
                vdst + ((dt * 2 + jj) * 2 + hiv) * 256 + lqv * 8 + ebase) = pk;
          }
        }
      } else {  // Q or K: RoPE (+ 1/sqrt(D) folded into Q), tiled store
        float invf[4];
#pragma unroll
        for (int j = 0; j < 4; ++j)
          invf[j] = exp2f(-(float)(j * 16 + li) * (13.287712379549449f / 64.0f));
        bf16* dst = ((seg == 0) ? (qb + (size_t)hh * S_LEN * HD)
                                : (kb + (size_t)hh * S_LEN * HD)) + (size_t)T * 4096;
        const float qscale = (seg == 0) ? 0.08838834764831845f : 1.0f;
        const int hi2 = li >> 3, e2 = li & 7;
#pragma unroll
        for (int mt = 0; mt < 2; ++mt)
#pragma unroll
          for (int r = 0; r < 4; ++r) {
            const int spos = row_base + mt * 16 + lh * 4 + r;
            const int lqr  = spos & 31;
            float cs[4], sn[4];
#pragma unroll
            for (int j = 0; j < 4; ++j) sincosf((float)spos * invf[j], &sn[j], &cs[j]);
#pragma unroll
            for (int nt = 0; nt < 8; ++nt) {
              const int j = nt & 3;
              const float x = acc[mt][nt][r];
              const float prt = acc[mt][nt ^ 4][r];
              const float rot = (nt < 4) ? -prt : prt;
              const float y = (x * cs[j] + rot * sn[j]) * qscale;
              dst[(nt * 2 + hi2) * 256 + lqr * 8 + e2] = (bf16)y;
            }
          }
      }
    }
  }
}

// ---------------- flash attention: LDS-shared K/V, 2 waves / 64 q-rows ----------------
// Block = 128 threads (2 waves). Wave ws owns q-rows [q0+32ws, q0+32ws+32).
// Both waves share every KV tile staged in LDS (wave0 stages K, wave1 stages V
// via global_load_lds, double-buffered; one vmcnt+barrier per tile). The
// epilogue transpose buffer Obf ALIASES the K/V staging space (dead after the
// final loop barrier) -> LDS 33KB -> 4 blocks/CU (8 waves/CU), whole grid
// co-resident. Static pairing keeps per-CU work constant.
__global__ __launch_bounds__(128, 2) void attn_kernel(
    const bf16* __restrict__ qb, const bf16* __restrict__ kb, const bf16* __restrict__ vtb,
    bf16* __restrict__ ctx)
{
  __shared__ __align__(16) char smem[33152];
  bf16* Kst = (bf16*)smem;               // [2][4096] bf16 = 16 KB (loop only)
  bf16* Vst = (bf16*)(smem + 16384);     // [2][4096] bf16 = 16 KB (loop only)
  float* Obf = (float*)smem;             // [2][32][129] f32 (epilogue only, aliased)

  const int tid = threadIdx.x;
  const int ws = tid >> 6;      // wave id (0: stages K, 1: stages V)
  const int l  = tid & 63;
  const int lq = l & 31;
  const int hi = l >> 5;
  const int b  = (int)blockIdx.x;
  const int qp = (b < 256) ? (31 - (b >> 4)) : ((b - 256) >> 4);
  const int h  = b & 15;
  const int q0w = qp * 64 + ws * 32;   // this wave's q-subtile base
  const int kh  = h >> 2;
  const int nt  = 2 * qp + 2;          // staged tiles (wave1's range)
  const int ntw = 2 * qp + 1 + ws;     // tiles this wave computes

  const bf16* Qh = qb + (size_t)h * S_LEN * HD;
  const bf16* Kh = kb + (size_t)kh * S_LEN * HD;
  const bf16* Vh = vtb + (size_t)kh * S_LEN * HD;
  const bf16* stsrc = ws ? Vh : Kh;    // this wave's staging source

  const float L2E = 1.4426950408889634f;
  const float BIG = -3.0e38f;

  // hoist Q fragments (coalesced 1KB loads from tiled layout)
  const bf16* qtile = Qh + (size_t)(q0w >> 5) * 4096;
  bf16x8 qfr[8];
#pragma unroll
  for (int kc = 0; kc < 8; ++kc)
    qfr[kc] = *reinterpret_cast<const bf16x8*>(qtile + (kc * 2 + hi) * 256 + lq * 8);

  f32x16 o[4];
#pragma unroll
  for (int dt = 0; dt < 4; ++dt) o[dt] = zero16();
  float mrow = BIG, lrow = 0.f;

  // ---- stage tile 0 ----
  {
    const bf16* src = stsrc + l * 8;
    bf16* dst = (ws ? Vst : Kst);
#pragma unroll
    for (int c = 0; c < 8; ++c)
      __builtin_amdgcn_global_load_lds(
          (const __attribute__((address_space(1))) void*)(src + c * 512),
          (__attribute__((address_space(3))) void*)(dst + c * 512), 16, 0, 0);
  }
  __syncthreads();   // drains vmcnt before barrier (compiler semantics)

  for (int t = 0; t < nt; ++t) {
    const int cur = t & 1;
    // ---- issue next tile's staging early (hides under compute) ----
    if (t + 1 < nt) {
      const bf16* src = stsrc + (size_t)(t + 1) * 4096 + l * 8;
      bf16* dst = (ws ? Vst : Kst) + (cur ^ 1) * 4096;
#pragma unroll
      for (int c = 0; c < 8; ++c)
        __builtin_amdgcn_global_load_lds(
            (const __attribute__((address_space(1))) void*)(src + c * 512),
            (__attribute__((address_space(3))) void*)(dst + c * 512), 16, 0, 0);
    }
    if (t < ntw) {
      const bf16* kcur = Kst + cur * 4096;
      const bf16* vcur = Vst + cur * 4096;
      const int kv0 = t * 32;
      // ---- QK^T from LDS: S^T[kv][q], two chains of 4 ----
      bf16x8 kf[8];
#pragma unroll
      for (int kc = 0; kc < 8; ++kc)
        kf[kc] = *reinterpret_cast<const bf16x8*>(kcur + (kc * 2 + hi) * 256 + lq * 8);
      f32x16 sa = zero16(), sb = zero16();
      __builtin_amdgcn_s_setprio(1);
#pragma unroll
      for (int kc = 0; kc < 4; ++kc) {
        sa = mfma32(kf[kc], qfr[kc], sa);
        sb = mfma32(kf[kc + 4], qfr[kc + 4], sb);
      }
      __builtin_amdgcn_s_setprio(0);
      f32x16 s = sa + sb;
      // ---- causal mask (diagonal tiles only) ----
      const int q = q0w + lq;
      if (kv0 + 31 > q0w) {
#pragma unroll
        for (int r = 0; r < 16; ++r) {
          const int kvv = (r & 3) + 8 * (r >> 2) + 4 * hi;
          if (kv0 + kvv > q) s[r] = BIG;
        }
      }
      // ---- in-register online softmax with defer-max (THR=8) ----
      float pm = s[0];
#pragma unroll
      for (int r = 1; r < 16; ++r) pm = fmaxf(pm, s[r]);
      pm = fmaxf(pm, __shfl_xor(pm, 32));
      if (__any(pm > mrow + 8.f)) {
        const float mnew = fmaxf(mrow, pm);
        const float sc = (mrow < -1.0e37f) ? 0.f : exp2f((mrow - mnew) * L2E);
        mrow = mnew;
        lrow *= sc;
#pragma unroll
        for (int dt = 0; dt < 4; ++dt) o[dt] = o[dt] * sc;
      }
      bf16x8 pb0, pb1;
      float tsum = 0.f;
#pragma unroll
      for (int r = 0; r < 8; ++r) {
        const float pv = exp2f((s[r] - mrow) * L2E);
        tsum += pv; pb0[r] = (bf16)pv;
      }
#pragma unroll
      for (int r = 0; r < 8; ++r) {
        const float pv = exp2f((s[8 + r] - mrow) * L2E);
        tsum += pv; pb1[r] = (bf16)pv;
      }
      tsum += __shfl_xor(tsum, 32);
      lrow += tsum;
      // ---- PV from LDS ----
      bf16x8 va[8];
#pragma unroll
      for (int sv = 0; sv < 8; ++sv)
        va[sv] = *reinterpret_cast<const bf16x8*>(vcur + (sv * 2 + hi) * 256 + lq * 8);
      __builtin_amdgcn_s_setprio(1);
#pragma unroll
      for (int dt = 0; dt < 4; ++dt) {
        o[dt] = mfma32(va[2 * dt], pb0, o[dt]);
        o[dt] = mfma32(va[2 * dt + 1], pb1, o[dt]);
      }
      __builtin_amdgcn_s_setprio(0);
    }
    __syncthreads();   // staged tile complete + all reads of cur done
  }
  // After this point Kst/Vst are dead; smem is reused as Obf.

  // ---- epilogue: per-wave LDS transpose, coalesced bf16 write ----
  {
    const float linv = 1.0f / lrow;
    float* obw = Obf + ws * (32 * 129);
#pragma unroll
    for (int dt = 0; dt < 4; ++dt)
#pragma unroll
      for (int r = 0; r < 16; ++r) {
        const int d = dt * 32 + (r & 3) + 8 * (r >> 2) + 4 * hi;
        obw[lq * 129 + d] = o[dt][r] * linv;
      }
    __syncthreads();
    const int row = l >> 1;
    const int dh  = (l & 1) * 64;
    const float* orow = Obf + ws * (32 * 129) + row * 129;
#pragma unroll
    for (int j = 0; j < 8; ++j) {
      bf16x8 pk;
#pragma unroll
      for (int e = 0; e < 8; ++e) pk[e] = (bf16)orow[dh + j * 8 + e];
      *reinterpret_cast<bf16x8*>(
          ctx + (size_t)(q0w + row) * (NH * HD) + h * HD + dh + j * 8) = pk;
    }
  }
}

extern "C" void kernel_launch(void* const* d_in, const int* in_sizes, int n_in,
                              void* d_out, int out_size, void* d_ws, size_t ws_size,
                              hipStream_t stream)
{
  const float* x       = (const float*)d_in[0];
  const float* w_qkv   = (const float*)d_in[1];
  const float* w_dense = (const float*)d_in[2];
  float* out = (float*)d_out;

  char* ws = (char*)d_ws;
  size_t off = 0;
  bf16* xb    = (bf16*)(ws + off); off += (size_t)S_LEN * EMB * 2;
  bf16* wqkvb = (bf16*)(ws + off); off += (size_t)FQKV * EMB * 2;
  bf16* wdb   = (bf16*)(ws + off); off += (size_t)EMB * EMB * 2;
  bf16* qbuf  = (bf16*)(ws + off); off += (size_t)NH  * S_LEN * HD * 2;
  bf16* kbuf  = (bf16*)(ws + off); off += (size_t)NKV * S_LEN * HD * 2;
  bf16* vfbuf = (bf16*)(ws + off); off += (size_t)NKV * HD * S_LEN * 2;
  bf16* ctxb  = (bf16*)(ws + off); off += (size_t)S_LEN * NH * HD * 2;
  (void)ws_size; (void)in_sizes; (void)n_in; (void)out_size;

  cvt_kernel<<<2048, 256, 0, stream>>>(x,       xb,    S_LEN * EMB / 4);
  cvt_kernel<<<2048, 256, 0, stream>>>(w_qkv,   wqkvb, FQKV * EMB / 4);
  cvt_kernel<<<2048, 256, 0, stream>>>(w_dense, wdb,   EMB * EMB / 4);

  gemm_bt<128><<<dim3(FQKV / 128, S_LEN / 128), 256, 0, stream>>>(
      xb, wqkvb, S_LEN, FQKV, EMB, 0, qbuf, kbuf, vfbuf, nullptr);

  attn_kernel<<<512, 128, 0, stream>>>(qbuf, kbuf, vfbuf, ctxb);

  gemm_bt<64><<<dim3(EMB / 64, S_LEN / 128), 256, 0, stream>>>(
      ctxb, wdb, S_LEN, EMB, NH * HD, 1, nullptr, nullptr, nullptr, out);
}

// Round 12
// 138.368 us; speedup vs baseline: 1.4390x; 1.1734x over previous
//
#include <hip/hip_runtime.h>
#include <hip/hip_bf16.h>
#include <math.h>

typedef __bf16 bf16;
typedef __bf16 bf16x4 __attribute__((ext_vector_type(4)));
typedef __bf16 bf16x8 __attribute__((ext_vector_type(8)));
typedef float  f32x4  __attribute__((ext_vector_type(4)));
typedef float  f32x16 __attribute__((ext_vector_type(16)));

#define S_LEN 2048
#define EMB   2048
#define NH    16
#define NKV   4
#define HD    128
#define FQKV  3072  /* NH*HD + 2*NKV*HD */

__device__ __forceinline__ f32x4 mfma16(bf16x8 a, bf16x8 b, f32x4 c) {
  return __builtin_amdgcn_mfma_f32_16x16x32_bf16(a, b, c, 0, 0, 0);
}
__device__ __forceinline__ f32x16 mfma32(bf16x8 a, bf16x8 b, f32x16 c) {
  return __builtin_amdgcn_mfma_f32_32x32x16_bf16(a, b, c, 0, 0, 0);
}
__device__ __forceinline__ f32x16 zero16() {
  f32x16 v;
#pragma unroll
  for (int i = 0; i < 16; ++i) v[i] = 0.f;
  return v;
}

// ---------------- f32 -> bf16 convert, 4-wide ----------------
__global__ void cvt_kernel(const float* __restrict__ in, bf16* __restrict__ out, int n4) {
  int i = blockIdx.x * blockDim.x + threadIdx.x;
  const int stride = gridDim.x * blockDim.x;
  for (; i < n4; i += stride) {
    float4 v = reinterpret_cast<const float4*>(in)[i];
    bf16x4 o;
    o[0] = (bf16)v.x; o[1] = (bf16)v.y; o[2] = (bf16)v.z; o[3] = (bf16)v.w;
    reinterpret_cast<bf16x4*>(out)[i] = o;
  }
}

// ---------------- GEMM: C[M][N] = A[M][K] * B[N][K]^T, tile 128 x BN ----------------
// BN=128 mode 0: fused RoPE/split epilogue, Q/K/V in fragment-ready TILED layouts
//   (per head, per 32-row tile T, elem addr = T*4096 + slot*256 + lq*8 + e):
//   Q/K: slot = kc*2 + hi;  V: slot = (dt*2+j)*2 + hi with kv-slot perm baked in.
// BN=64 mode 1: plain f32 store (512 blocks -> 2 blocks/CU for the dense GEMM).
template<int BN>
__global__ __launch_bounds__(256, 2) void gemm_bt(
    const bf16* __restrict__ A, const bf16* __restrict__ B,
    int M, int N, int K, int mode,
    bf16* __restrict__ qb, bf16* __restrict__ kb, bf16* __restrict__ vtb,
    float* __restrict__ outf)
{
  constexpr int NFR = BN / 16;
  __shared__ __align__(16) bf16 As[128 * 64];
  __shared__ __align__(16) bf16 Bs[BN * 64];
  const int tid = threadIdx.x;
  const int w  = tid >> 6;
  const int l  = tid & 63;
  const int li = l & 15, lh = l >> 4;
  const int m0 = blockIdx.y * 128, n0 = blockIdx.x * BN;

  f32x4 acc[2][NFR];
#pragma unroll
  for (int i = 0; i < 2; ++i)
#pragma unroll
    for (int j = 0; j < NFR; ++j) acc[i][j] = f32x4{0.f, 0.f, 0.f, 0.f};

  const int srow = l >> 3;   // row within an 8-row staging group
  const int schk = l & 7;    // 16B chunk within a 64-col row

  for (int k0 = 0; k0 < K; k0 += 64) {
#pragma unroll
    for (int i = 0; i < 4; ++i) {          // A: 128 rows
      const int row = i * 32 + w * 8 + srow;
      const int sch = schk ^ (row & 7);
      const bf16* ga = A + (size_t)(m0 + row) * K + (k0 + sch * 8);
      bf16* la = As + (i * 32 + w * 8) * 64;
      __builtin_amdgcn_global_load_lds((const __attribute__((address_space(1))) void*)ga,
                                       (__attribute__((address_space(3))) void*)la, 16, 0, 0);
    }
#pragma unroll
    for (int i = 0; i < BN / 32; ++i) {    // B: BN rows
      const int row = i * 32 + w * 8 + srow;
      const int sch = schk ^ (row & 7);
      const bf16* gb = B + (size_t)(n0 + row) * K + (k0 + sch * 8);
      bf16* lb = Bs + (i * 32 + w * 8) * 64;
      __builtin_amdgcn_global_load_lds((const __attribute__((address_space(1))) void*)gb,
                                       (__attribute__((address_space(3))) void*)lb, 16, 0, 0);
    }
    __syncthreads();
#pragma unroll
    for (int kc = 0; kc < 2; ++kc) {
      bf16x8 afr[2], bfr[NFR];
#pragma unroll
      for (int mt = 0; mt < 2; ++mt) {
        const int mr = w * 32 + mt * 16 + li;
        const int c  = (kc * 4 + lh) ^ (mr & 7);
        afr[mt] = *reinterpret_cast<const bf16x8*>((const char*)As + mr * 128 + c * 16);
      }
#pragma unroll
      for (int nt = 0; nt < NFR; ++nt) {
        const int nr = nt * 16 + li;
        const int c  = (kc * 4 + lh) ^ (nr & 7);
        bfr[nt] = *reinterpret_cast<const bf16x8*>((const char*)Bs + nr * 128 + c * 16);
      }
#pragma unroll
      for (int nt = 0; nt < NFR; ++nt) {
        acc[0][nt] = mfma16(afr[0], bfr[nt], acc[0][nt]);
        acc[1][nt] = mfma16(afr[1], bfr[nt], acc[1][nt]);
      }
    }
    __syncthreads();
  }

  // ---- epilogue ----
  const int row_base = m0 + w * 32;
  if (BN == 64 || mode == 1) {
#pragma unroll
    for (int mt = 0; mt < 2; ++mt)
#pragma unroll
      for (int nt = 0; nt < NFR; ++nt)
#pragma unroll
        for (int r = 0; r < 4; ++r) {
          const int sr = row_base + mt * 16 + lh * 4 + r;
          const int sc = n0 + nt * 16 + li;
          outf[(size_t)sr * N + sc] = acc[mt][nt][r];
        }
  } else {
    if constexpr (BN == 128) {
      int seg, hh;
      if (n0 < NH * HD)             { seg = 0; hh = n0 >> 7; }
      else if (n0 < (NH + NKV) * HD){ seg = 1; hh = (n0 - NH * HD) >> 7; }
      else                          { seg = 2; hh = (n0 - (NH + NKV) * HD) >> 7; }

      const int T = row_base >> 5;          // 32-row tile index (constant per wave)
      if (seg == 2) {
        // V tiled store: acc[mt][nt][r] = V[spos][d], spos = row_base + qp*4 + r,
        // qp = mt*4+lh; d = nt*16+li -> dt = nt>>1, lqv = (nt&1)*16+li.
        // j=(qp>>2)&1, hiv=qp&1, e = 4*((qp>>1)&1) + r
        bf16* vdst = vtb + (size_t)hh * S_LEN * HD + (size_t)T * 4096;
#pragma unroll
        for (int mt = 0; mt < 2; ++mt) {
          const int qp = mt * 4 + lh;
          const int jj = (qp >> 2) & 1, hiv = qp & 1, ebase = 4 * ((qp >> 1) & 1);
#pragma unroll
          for (int nt = 0; nt < 8; ++nt) {
            const int dt = nt >> 1;
            const int lqv = (nt & 1) * 16 + li;
            bf16x4 pk;
#pragma unroll
            for (int r = 0; r < 4; ++r) pk[r] = (bf16)acc[mt][nt][r];
            *reinterpret_cast<bf16x4*>(
                vdst + ((dt * 2 + jj) * 2 + hiv) * 256 + lqv * 8 + ebase) = pk;
          }
        }
      } else {  // Q or K: RoPE (+ 1/sqrt(D) folded into Q), tiled store
        float invf[4];
#pragma unroll
        for (int j = 0; j < 4; ++j)
          invf[j] = exp2f(-(float)(j * 16 + li) * (13.287712379549449f / 64.0f));
        bf16* dst = ((seg == 0) ? (qb + (size_t)hh * S_LEN * HD)
                                : (kb + (size_t)hh * S_LEN * HD)) + (size_t)T * 4096;
        const float qscale = (seg == 0) ? 0.08838834764831845f : 1.0f;
        const int hi2 = li >> 3, e2 = li & 7;
#pragma unroll
        for (int mt = 0; mt < 2; ++mt)
#pragma unroll
          for (int r = 0; r < 4; ++r) {
            const int spos = row_base + mt * 16 + lh * 4 + r;
            const int lqr  = spos & 31;
            float cs[4], sn[4];
#pragma unroll
            for (int j = 0; j < 4; ++j) sincosf((float)spos * invf[j], &sn[j], &cs[j]);
#pragma unroll
            for (int nt = 0; nt < 8; ++nt) {
              const int j = nt & 3;
              const float x = acc[mt][nt][r];
              const float prt = acc[mt][nt ^ 4][r];
              const float rot = (nt < 4) ? -prt : prt;
              const float y = (x * cs[j] + rot * sn[j]) * qscale;
              dst[(nt * 2 + hi2) * 256 + lqr * 8 + e2] = (bf16)y;
            }
          }
      }
    }
  }
}

// ---------------- flash attention: independent-wave pipeline ----------------
// 1024 blocks x 128 thr. Block (qt, h) owns 32 q-rows; its 2 waves split KV by
// parity (wave w: tiles t = w, w+2, ...), each with a PRIVATE 16KB K/V staging
// buffer and single-buffered DMA pipeline: vmcnt(0) -> ds_read all frags ->
// lgkmcnt(0) -> issue next tile's DMAs into the vacated buffer -> compute.
// NO in-loop barriers. 2-way (m,l,O) merge at the end through aliased LDS.
// qt layering (63-b, 32+b, 31-b, b) keeps per-CU totals constant.
__global__ __launch_bounds__(128, 2) void attn_kernel(
    const bf16* __restrict__ qb, const bf16* __restrict__ kb, const bf16* __restrict__ vtb,
    bf16* __restrict__ ctx)
{
  __shared__ __align__(16) char smem[33280];   // 2 x 16KB wave K/V bufs; aliased Obf
  __shared__ float Ml[2][32], Ll[2][32], Lgl[32];
  float* Obf = (float*)smem;                   // [32][129] f32 (epilogue only)

  const int tid = threadIdx.x;
  const int ws = tid >> 6;      // wave id = kv parity
  const int l  = tid & 63;
  const int lq = l & 31;
  const int hi = l >> 5;
  const int b  = (int)blockIdx.x;
  const int layer = b >> 8, idx = b & 255;
  const int h    = idx & 15;
  const int base = idx >> 4;
  const int qt   = (layer == 0) ? (63 - base)
                 : (layer == 1) ? (32 + base)
                 : (layer == 2) ? (31 - base) : base;
  const int q0 = qt * 32;
  const int kh = h >> 2;

  bf16* Kbuf = (bf16*)(smem + ws * 16384);          // 8 KB
  bf16* Vbuf = (bf16*)(smem + ws * 16384 + 8192);   // 8 KB

  const bf16* Qh = qb + (size_t)h * S_LEN * HD;
  const bf16* Kh = kb + (size_t)kh * S_LEN * HD;
  const bf16* Vh = vtb + (size_t)kh * S_LEN * HD;

  const float L2E = 1.4426950408889634f;
  const float BIG = -3.0e38f;

  // hoist Q fragments (coalesced 1KB loads from tiled layout)
  const bf16* qtile = Qh + (size_t)qt * 4096;
  bf16x8 qfr[8];
#pragma unroll
  for (int kc = 0; kc < 8; ++kc)
    qfr[kc] = *reinterpret_cast<const bf16x8*>(qtile + (kc * 2 + hi) * 256 + lq * 8);

  f32x16 o[4];
#pragma unroll
  for (int dt = 0; dt < 4; ++dt) o[dt] = zero16();
  float mrow = BIG, lrow = 0.f;

  // ---- prologue: stage this wave's first tile ----
  if (ws <= qt) {
    const bf16* ksrc = Kh + (size_t)ws * 4096 + l * 8;
    const bf16* vsrc = Vh + (size_t)ws * 4096 + l * 8;
#pragma unroll
    for (int c = 0; c < 8; ++c) {
      __builtin_amdgcn_global_load_lds(
          (const __attribute__((address_space(1))) void*)(ksrc + c * 512),
          (__attribute__((address_space(3))) void*)(Kbuf + c * 512), 16, 0, 0);
      __builtin_amdgcn_global_load_lds(
          (const __attribute__((address_space(1))) void*)(vsrc + c * 512),
          (__attribute__((address_space(3))) void*)(Vbuf + c * 512), 16, 0, 0);
    }
  }

  for (int t = ws; t <= qt; t += 2) {
    // ---- wait for this tile's staging, read all fragments to regs ----
    asm volatile("s_waitcnt vmcnt(0)" ::: "memory");
    __builtin_amdgcn_sched_barrier(0);
    bf16x8 kf[8], va[8];
#pragma unroll
    for (int kc = 0; kc < 8; ++kc)
      kf[kc] = *reinterpret_cast<const bf16x8*>(Kbuf + (kc * 2 + hi) * 256 + lq * 8);
#pragma unroll
    for (int sv = 0; sv < 8; ++sv)
      va[sv] = *reinterpret_cast<const bf16x8*>(Vbuf + (sv * 2 + hi) * 256 + lq * 8);
    asm volatile("s_waitcnt lgkmcnt(0)" ::: "memory");
    __builtin_amdgcn_sched_barrier(0);
    // ---- issue next parity tile's DMAs into the vacated buffer ----
    if (t + 2 <= qt) {
      const bf16* ksrc = Kh + (size_t)(t + 2) * 4096 + l * 8;
      const bf16* vsrc = Vh + (size_t)(t + 2) * 4096 + l * 8;
#pragma unroll
      for (int c = 0; c < 8; ++c) {
        __builtin_amdgcn_global_load_lds(
            (const __attribute__((address_space(1))) void*)(ksrc + c * 512),
            (__attribute__((address_space(3))) void*)(Kbuf + c * 512), 16, 0, 0);
        __builtin_amdgcn_global_load_lds(
            (const __attribute__((address_space(1))) void*)(vsrc + c * 512),
            (__attribute__((address_space(3))) void*)(Vbuf + c * 512), 16, 0, 0);
      }
    }
    // ---- QK^T: S^T[kv][q], two chains of 4 ----
    f32x16 sa = zero16(), sb = zero16();
    __builtin_amdgcn_s_setprio(1);
#pragma unroll
    for (int kc = 0; kc < 4; ++kc) {
      sa = mfma32(kf[kc], qfr[kc], sa);
      sb = mfma32(kf[kc + 4], qfr[kc + 4], sb);
    }
    __builtin_amdgcn_s_setprio(0);
    f32x16 s = sa + sb;
    // ---- causal mask (diagonal tile only) ----
    if (t == qt) {
      const int q = q0 + lq;
#pragma unroll
      for (int r = 0; r < 16; ++r) {
        const int kvv = (r & 3) + 8 * (r >> 2) + 4 * hi;
        if (t * 32 + kvv > q) s[r] = BIG;
      }
    }
    // ---- in-register online softmax with defer-max (THR=8) ----
    float pm = s[0];
#pragma unroll
    for (int r = 1; r < 16; ++r) pm = fmaxf(pm, s[r]);
    pm = fmaxf(pm, __shfl_xor(pm, 32));
    if (__any(pm > mrow + 8.f)) {
      const float mnew = fmaxf(mrow, pm);
      const float sc = (mrow < -1.0e37f) ? 0.f : exp2f((mrow - mnew) * L2E);
      mrow = mnew;
      lrow *= sc;
#pragma unroll
      for (int dt = 0; dt < 4; ++dt) o[dt] = o[dt] * sc;
    }
    bf16x8 pb0, pb1;
    float tsum = 0.f;
#pragma unroll
    for (int r = 0; r < 8; ++r) {
      const float pv = exp2f((s[r] - mrow) * L2E);
      tsum += pv; pb0[r] = (bf16)pv;
    }
#pragma unroll
    for (int r = 0; r < 8; ++r) {
      const float pv = exp2f((s[8 + r] - mrow) * L2E);
      tsum += pv; pb1[r] = (bf16)pv;
    }
    tsum += __shfl_xor(tsum, 32);
    lrow += tsum;
    // ---- PV ----
    __builtin_amdgcn_s_setprio(1);
#pragma unroll
    for (int dt = 0; dt < 4; ++dt) {
      o[dt] = mfma32(va[2 * dt], pb0, o[dt]);
      o[dt] = mfma32(va[2 * dt + 1], pb1, o[dt]);
    }
    __builtin_amdgcn_s_setprio(0);
  }

  // ---- 2-way parity merge (Obf aliases the K/V buffers, dead after loops) ----
  if (hi == 0) { Ml[ws][lq] = mrow; Ll[ws][lq] = lrow; }
  __syncthreads();   // both waves' loops done -> safe to alias Obf
  const float m0v = Ml[0][lq], m1v = Ml[1][lq];
  const float mg = fmaxf(m0v, m1v);
  const float lg = Ll[0][lq] * exp2f((m0v - mg) * L2E)
                 + Ll[1][lq] * exp2f((m1v - mg) * L2E);
  const float sc2 = (mrow < -1.0e37f) ? 0.f : exp2f((mrow - mg) * L2E);
  if (ws == 0 && hi == 0) Lgl[lq] = lg;
#pragma unroll
  for (int pass = 0; pass < 2; ++pass) {
    if (ws == pass) {
#pragma unroll
      for (int dt = 0; dt < 4; ++dt)
#pragma unroll
        for (int r = 0; r < 16; ++r) {
          const int d = dt * 32 + (r & 3) + 8 * (r >> 2) + 4 * hi;
          const float v = o[dt][r] * sc2;
          if (pass == 0) Obf[lq * 129 + d] = v; else Obf[lq * 129 + d] += v;
        }
    }
    __syncthreads();
  }
  // ---- epilogue: 128 threads, row = tid>>2, 32 d each ----
  {
    const int row = tid >> 2;
    const int d0 = (tid & 3) * 32;
    const float linv = 1.0f / Lgl[row];
    const float* orow = Obf + row * 129 + d0;
    bf16* dst = ctx + (size_t)(q0 + row) * (NH * HD) + h * HD + d0;
#pragma unroll
    for (int j = 0; j < 4; ++j) {
      bf16x8 pk;
#pragma unroll
      for (int e = 0; e < 8; ++e) pk[e] = (bf16)(orow[j * 8 + e] * linv);
      *reinterpret_cast<bf16x8*>(dst + j * 8) = pk;
    }
  }
}

extern "C" void kernel_launch(void* const* d_in, const int* in_sizes, int n_in,
                              void* d_out, int out_size, void* d_ws, size_t ws_size,
                              hipStream_t stream)
{
  const float* x       = (const float*)d_in[0];
  const float* w_qkv   = (const float*)d_in[1];
  const float* w_dense = (const float*)d_in[2];
  float* out = (float*)d_out;

  char* ws = (char*)d_ws;
  size_t off = 0;
  bf16* xb    = (bf16*)(ws + off); off += (size_t)S_LEN * EMB * 2;
  bf16* wqkvb = (bf16*)(ws + off); off += (size_t)FQKV * EMB * 2;
  bf16* wdb   = (bf16*)(ws + off); off += (size_t)EMB * EMB * 2;
  bf16* qbuf  = (bf16*)(ws + off); off += (size_t)NH  * S_LEN * HD * 2;
  bf16* kbuf  = (bf16*)(ws + off); off += (size_t)NKV * S_LEN * HD * 2;
  bf16* vfbuf = (bf16*)(ws + off); off += (size_t)NKV * HD * S_LEN * 2;
  bf16* ctxb  = (bf16*)(ws + off); off += (size_t)S_LEN * NH * HD * 2;
  (void)ws_size; (void)in_sizes; (void)n_in; (void)out_size;

  cvt_kernel<<<2048, 256, 0, stream>>>(x,       xb,    S_LEN * EMB / 4);
  cvt_kernel<<<2048, 256, 0, stream>>>(w_qkv,   wqkvb, FQKV * EMB / 4);
  cvt_kernel<<<2048, 256, 0, stream>>>(w_dense, wdb,   EMB * EMB / 4);

  gemm_bt<128><<<dim3(FQKV / 128, S_LEN / 128), 256, 0, stream>>>(
      xb, wqkvb, S_LEN, FQKV, EMB, 0, qbuf, kbuf, vfbuf, nullptr);

  attn_kernel<<<1024, 128, 0, stream>>>(qbuf, kbuf, vfbuf, ctxb);

  gemm_bt<64><<<dim3(EMB / 64, S_LEN / 128), 256, 0, stream>>>(
      ctxb, wdb, S_LEN, EMB, NH * HD, 1, nullptr, nullptr, nullptr, out);
}